// Round 1
// baseline (109.833 us; speedup 1.0000x reference)
//
#include <hip/hip_runtime.h>

constexpr int D = 64;  // D_FEAT == UNITS == 64

// One wave per node. Block = 256 threads = 4 waves = 4 nodes.
__global__ __launch_bounds__(256, 4) void gcn_fused(
    const float* __restrict__ src,   // [N, 64]
    const float* __restrict__ dst,   // [E, 64]
    const int*   __restrict__ ids,   // [E] sorted ascending
    const float* __restrict__ Wm,    // [64, 64]
    const float* __restrict__ bv,    // [64]
    float*       __restrict__ out,   // [N, 64]
    int n_nodes, int n_edges)
{
    __shared__ float sW[D][D];   // 16 KB: W staged once per block
    __shared__ float sx[4][D];   // 1 KB: one x-row per wave

    const int tid = threadIdx.x;

    // Stage W: 4096 floats via float4, 4 per thread. Coalesced, conflict-free.
    {
        const float4* W4  = (const float4*)Wm;
        float4*       sW4 = (float4*)&sW[0][0];
#pragma unroll
        for (int i = 0; i < 4; ++i) sW4[tid + 256 * i] = W4[tid + 256 * i];
    }
    __syncthreads();  // only barrier; before any wave-divergent exit

    const int wave = tid >> 6;
    const int lane = tid & 63;
    const int node = blockIdx.x * 4 + wave;
    if (node >= n_nodes) return;  // never taken for N=50000 (divisible by 4)

    // lower_bound(ids, node) in lanes 0..31, lower_bound(ids, node+1) in lanes 32..63.
    // Uniform per half-wave -> 2 cache lines per step, ids (5MB) L2/L3-resident.
    {
        // nothing
    }
    const int key = node + (lane >> 5);
    int lo = 0, hi = n_edges;
    while (lo < hi) {
        const int mid = (lo + hi) >> 1;
        if (ids[mid] < key) lo = mid + 1; else hi = mid;
    }
    const int start = __shfl(lo, 0);
    const int end   = __shfl(lo, 32);
    const int cnt   = end - start;

    // Edge sum. 16-lane group g (=lane>>4) takes edges start+g, start+g+4, ...
    // Lane covers features [4f, 4f+4) via float4: 64 lanes x 16B = 1KB/instr, contiguous.
    const int g = lane >> 4;
    const int f = lane & 15;

    float4 a = make_float4(0.f, 0.f, 0.f, 0.f);
    int e = start + g;
    const float4* p = (const float4*)dst + (size_t)e * (D / 4) + f;
    // unroll x2: two independent loads in flight per wave
    for (; e + 4 < end; e += 8, p += 128) {
        const float4 v0 = p[0];
        const float4 v1 = p[64];
        a.x += v0.x + v1.x;
        a.y += v0.y + v1.y;
        a.z += v0.z + v1.z;
        a.w += v0.w + v1.w;
    }
    if (e < end) {
        const float4 v0 = p[0];
        a.x += v0.x; a.y += v0.y; a.z += v0.z; a.w += v0.w;
    }

    // Reduce the 4 groups (lanes f, f+16, f+32, f+48) -> every lane has full sums.
    a.x += __shfl_xor(a.x, 16); a.y += __shfl_xor(a.y, 16);
    a.z += __shfl_xor(a.z, 16); a.w += __shfl_xor(a.w, 16);
    a.x += __shfl_xor(a.x, 32); a.y += __shfl_xor(a.y, 32);
    a.z += __shfl_xor(a.z, 32); a.w += __shfl_xor(a.w, 32);

    // x = mean + src, staged to LDS by lanes 0..15 (float4 each).
    if (lane < 16) {
        const float  inv = 1.0f / fmaxf((float)cnt, 1.0f);
        const float4 s4  = *((const float4*)(src + (size_t)node * D) + f);
        float4 xv;
        xv.x = fmaf(a.x, inv, s4.x);
        xv.y = fmaf(a.y, inv, s4.y);
        xv.z = fmaf(a.z, inv, s4.z);
        xv.w = fmaf(a.w, inv, s4.w);
        *((float4*)&sx[wave][0] + f) = xv;
    }
    // same-wave LDS RAW: compiler inserts lgkmcnt wait (no barrier needed;
    // each wave only touches sx[wave]).

    // out[node][lane] = b[lane] + sum_k x[k] * W[k][lane]
    float acc = bv[lane];
#pragma unroll
    for (int k = 0; k < D; k += 4) {
        const float4 xk = *(const float4*)&sx[wave][k];  // broadcast (same addr)
        acc = fmaf(xk.x, sW[k + 0][lane], acc);          // stride-1: conflict-free
        acc = fmaf(xk.y, sW[k + 1][lane], acc);
        acc = fmaf(xk.z, sW[k + 2][lane], acc);
        acc = fmaf(xk.w, sW[k + 3][lane], acc);
    }
    out[(size_t)node * D + lane] = acc;
}

extern "C" void kernel_launch(void* const* d_in, const int* in_sizes, int n_in,
                              void* d_out, int out_size, void* d_ws, size_t ws_size,
                              hipStream_t stream) {
    const float* src = (const float*)d_in[0];
    // d_in[1] = edge (unused by reference)
    const float* dst = (const float*)d_in[2];
    const int*   ids = (const int*)d_in[3];
    const float* Wm  = (const float*)d_in[4];
    const float* bv  = (const float*)d_in[5];
    float* out = (float*)d_out;

    const int n_nodes = in_sizes[0] / D;   // 50000
    const int n_edges = in_sizes[3];       // 1250000

    const int blocks = (n_nodes + 3) / 4;  // 12500
    gcn_fused<<<blocks, 256, 0, stream>>>(src, dst, ids, Wm, bv, out, n_nodes, n_edges);
}

// Round 2
// 76.140 us; speedup vs baseline: 1.4425x; 1.4425x over previous
//
#include <hip/hip_runtime.h>

constexpr int D = 64;  // D_FEAT == UNITS == 64

// ---------------------------------------------------------------------------
// Kernel A (edge-centric): offs[n] = lower_bound(ids, n) for n in [0, N].
// ids sorted ascending. Where ids jumps from prev to cur, nodes prev+1..cur
// get offset e; nodes beyond ids[E-1] get E. Each offs[n] written exactly once.
// ---------------------------------------------------------------------------
__global__ void seg_bounds(const int* __restrict__ ids, int* __restrict__ offs,
                           int n_nodes, int n_edges) {
    const int e = blockIdx.x * blockDim.x + threadIdx.x;
    if (e >= n_edges) return;
    const int cur  = ids[e];
    const int prev = (e == 0) ? -1 : ids[e - 1];
    for (int n = prev + 1; n <= cur; ++n) offs[n] = e;
    if (e == n_edges - 1) {
        for (int n = cur + 1; n <= n_nodes; ++n) offs[n] = n_edges;
    }
}

// ---------------------------------------------------------------------------
// Kernel B: one wave per node. Block = 256 = 4 waves = 4 nodes.
// USE_OFFS: read precomputed [offs[n], offs[n+1]) instead of binary search.
// ---------------------------------------------------------------------------
template <bool USE_OFFS>
__global__ __launch_bounds__(256, 6) void gcn_fused(
    const float* __restrict__ src,   // [N, 64]
    const float* __restrict__ dst,   // [E, 64]
    const int*   __restrict__ ids,   // [E] sorted (fallback path only)
    const int*   __restrict__ offs,  // [N+1] segment offsets
    const float* __restrict__ Wm,    // [64, 64]
    const float* __restrict__ bv,    // [64]
    float*       __restrict__ out,   // [N, 64]
    int n_nodes, int n_edges)
{
    __shared__ float sW[D][D];   // 16 KB
    __shared__ float sx[4][D];   // 1 KB

    const int tid = threadIdx.x;

    // Stage W: 4096 floats via float4. Coalesced, conflict-free.
    {
        const float4* W4  = (const float4*)Wm;
        float4*       sW4 = (float4*)&sW[0][0];
#pragma unroll
        for (int i = 0; i < 4; ++i) sW4[tid + 256 * i] = W4[tid + 256 * i];
    }
    __syncthreads();  // only barrier; before any divergent exit

    const int wave = tid >> 6;
    const int lane = tid & 63;
    const int node = blockIdx.x * 4 + wave;
    if (node >= n_nodes) return;  // never taken (50000 % 4 == 0)

    int start_, end_;
    if (USE_OFFS) {
        start_ = offs[node];       // wave-uniform -> scalarized broadcast load
        end_   = offs[node + 1];
    } else {
        const int key = node + (lane >> 5);
        int lo = 0, hi = n_edges;
        while (lo < hi) {
            const int mid = (lo + hi) >> 1;
            if (ids[mid] < key) lo = mid + 1; else hi = mid;
        }
        start_ = __shfl(lo, 0);
        end_   = __shfl(lo, 32);
    }
    const int cnt = end_ - start_;

    // Edge sum. Group g (=lane>>4) takes edges start+g, start+g+4, ...
    // Each load instr: 64 lanes x 16B = 1KB = 4 contiguous edge rows.
    const int g = lane >> 4;
    const int f = lane & 15;

    float4 a = make_float4(0.f, 0.f, 0.f, 0.f);
    int e = start_ + g;
    const float4* p = (const float4*)dst + (size_t)e * (D / 4) + f;

    // main loop: 16 edge rows / iter, 4 loads (4KB) in flight per wave
    for (; e + 12 < end_; e += 16, p += 256) {
        const float4 v0 = p[0];
        const float4 v1 = p[64];
        const float4 v2 = p[128];
        const float4 v3 = p[192];
        a.x += (v0.x + v1.x) + (v2.x + v3.x);
        a.y += (v0.y + v1.y) + (v2.y + v3.y);
        a.z += (v0.z + v1.z) + (v2.z + v3.z);
        a.w += (v0.w + v1.w) + (v2.w + v3.w);
    }
    // tail: <=3 iterations of 4 rows
    for (; e < end_; e += 4, p += 64) {
        const float4 v = p[0];
        a.x += v.x; a.y += v.y; a.z += v.z; a.w += v.w;
    }

    // Reduce the 4 groups -> every lane has full feature sums.
    a.x += __shfl_xor(a.x, 16); a.y += __shfl_xor(a.y, 16);
    a.z += __shfl_xor(a.z, 16); a.w += __shfl_xor(a.w, 16);
    a.x += __shfl_xor(a.x, 32); a.y += __shfl_xor(a.y, 32);
    a.z += __shfl_xor(a.z, 32); a.w += __shfl_xor(a.w, 32);

    // x = mean + src, staged to LDS by lanes 0..15.
    if (lane < 16) {
        const float  inv = 1.0f / fmaxf((float)cnt, 1.0f);
        const float4 s4  = *((const float4*)(src + (size_t)node * D) + f);
        float4 xv;
        xv.x = fmaf(a.x, inv, s4.x);
        xv.y = fmaf(a.y, inv, s4.y);
        xv.z = fmaf(a.z, inv, s4.z);
        xv.w = fmaf(a.w, inv, s4.w);
        *((float4*)&sx[wave][0] + f) = xv;
    }
    // same-wave LDS RAW: compiler inserts lgkmcnt wait; no barrier needed
    // (each wave only touches sx[wave]).

    // out[node][lane] = b[lane] + sum_k x[k] * W[k][lane]
    float acc = bv[lane];
#pragma unroll
    for (int k = 0; k < D; k += 4) {
        const float4 xk = *(const float4*)&sx[wave][k];  // broadcast
        acc = fmaf(xk.x, sW[k + 0][lane], acc);          // 2-way bank alias: free
        acc = fmaf(xk.y, sW[k + 1][lane], acc);
        acc = fmaf(xk.z, sW[k + 2][lane], acc);
        acc = fmaf(xk.w, sW[k + 3][lane], acc);
    }
    out[(size_t)node * D + lane] = acc;
}

extern "C" void kernel_launch(void* const* d_in, const int* in_sizes, int n_in,
                              void* d_out, int out_size, void* d_ws, size_t ws_size,
                              hipStream_t stream) {
    const float* src = (const float*)d_in[0];
    // d_in[1] = edge (unused by reference)
    const float* dst = (const float*)d_in[2];
    const int*   ids = (const int*)d_in[3];
    const float* Wm  = (const float*)d_in[4];
    const float* bv  = (const float*)d_in[5];
    float* out = (float*)d_out;

    const int n_nodes = in_sizes[0] / D;   // 50000
    const int n_edges = in_sizes[3];       // 1250000

    const int nblocks = (n_nodes + 3) / 4; // 12500

    if (ws_size >= (size_t)(n_nodes + 1) * sizeof(int)) {
        int* offs = (int*)d_ws;
        seg_bounds<<<(n_edges + 255) / 256, 256, 0, stream>>>(ids, offs, n_nodes, n_edges);
        gcn_fused<true><<<nblocks, 256, 0, stream>>>(src, dst, ids, offs, Wm, bv, out,
                                                     n_nodes, n_edges);
    } else {
        gcn_fused<false><<<nblocks, 256, 0, stream>>>(src, dst, ids, nullptr, Wm, bv, out,
                                                      n_nodes, n_edges);
    }
}

// Round 3
// 72.457 us; speedup vs baseline: 1.5158x; 1.0508x over previous
//
#include <hip/hip_runtime.h>

constexpr int D = 64;  // D_FEAT == UNITS == 64

// ---------------------------------------------------------------------------
// Kernel A (edge-centric): offs[n] = lower_bound(ids, n) for n in [0, N].
// ---------------------------------------------------------------------------
__global__ void seg_bounds(const int* __restrict__ ids, int* __restrict__ offs,
                           int n_nodes, int n_edges) {
    const int e = blockIdx.x * blockDim.x + threadIdx.x;
    if (e >= n_edges) return;
    const int cur  = ids[e];
    const int prev = (e == 0) ? -1 : ids[e - 1];
    for (int n = prev + 1; n <= cur; ++n) offs[n] = e;
    if (e == n_edges - 1) {
        for (int n = cur + 1; n <= n_nodes; ++n) offs[n] = n_edges;
    }
}

// ---------------------------------------------------------------------------
// Kernel B: one wave per node. Block = 256 = 4 waves = 4 nodes.
// Edge loop: predicated 4-row batches, unroll x4, no remainder loop ->
// always >=4 independent 1KB loads in flight; masked lanes clamp address to
// end-1 (cache-hot) and cndmask the accumulate.
// __launch_bounds__(256, 8): VGPR<=64 -> 32 waves/CU; LDS 8x17KB=136<=160KB.
// ---------------------------------------------------------------------------
template <bool USE_OFFS>
__global__ __launch_bounds__(256, 8) void gcn_fused(
    const float* __restrict__ src,   // [N, 64]
    const float* __restrict__ dst,   // [E, 64]
    const int*   __restrict__ ids,   // [E] sorted (fallback path only)
    const int*   __restrict__ offs,  // [N+1] segment offsets
    const float* __restrict__ Wm,    // [64, 64]
    const float* __restrict__ bv,    // [64]
    float*       __restrict__ out,   // [N, 64]
    int n_nodes, int n_edges)
{
    __shared__ float sW[D][D];   // 16 KB
    __shared__ float sx[4][D];   // 1 KB

    const int tid = threadIdx.x;

    // Stage W: 4096 floats via float4. Coalesced, conflict-free.
    {
        const float4* W4  = (const float4*)Wm;
        float4*       sW4 = (float4*)&sW[0][0];
#pragma unroll
        for (int i = 0; i < 4; ++i) sW4[tid + 256 * i] = W4[tid + 256 * i];
    }
    __syncthreads();  // only barrier; before any divergent exit

    const int wave = tid >> 6;
    const int lane = tid & 63;
    const int node = blockIdx.x * 4 + wave;
    if (node >= n_nodes) return;  // never taken (50000 % 4 == 0)

    int start_, end_;
    if (USE_OFFS) {
        start_ = offs[node];
        end_   = offs[node + 1];
    } else {
        const int key = node + (lane >> 5);
        int lo = 0, hi = n_edges;
        while (lo < hi) {
            const int mid = (lo + hi) >> 1;
            if (ids[mid] < key) lo = mid + 1; else hi = mid;
        }
        start_ = __shfl(lo, 0);
        end_   = __shfl(lo, 32);
    }
    const int cnt = end_ - start_;

    const int g = lane >> 4;   // 4 groups of 16 lanes; group g -> rows start+g+4b
    const int f = lane & 15;   // float4 chunk within a 256B row

    // Prefetch src row EARLY so its HBM latency hides under edge streaming.
    float4 s4 = make_float4(0.f, 0.f, 0.f, 0.f);
    if (lane < 16) s4 = *((const float4*)(src + (size_t)node * D) + f);

    const float4* dst4 = (const float4*)dst;
    float4 a = make_float4(0.f, 0.f, 0.f, 0.f);

    const int nb   = (cnt + 3) >> 2;       // 4-row batches needed
    const int nb4  = (nb + 3) & ~3;        // round up: no remainder loop
    const int last = end_ - 1;             // clamp target (valid iff cnt>0)

#pragma unroll 1
    for (int b = 0; b < nb4; b += 4) {
#pragma unroll
        for (int u = 0; u < 4; ++u) {
            const int r  = start_ + g + 4 * (b + u);
            const int rc = min(r, last);             // stay in-segment (hot line)
            const float4 v = dst4[rc * (D / 4) + f]; // rc*16+f < 20M: int ok
            const bool  m = (r < end_);
            a.x += m ? v.x : 0.0f;
            a.y += m ? v.y : 0.0f;
            a.z += m ? v.z : 0.0f;
            a.w += m ? v.w : 0.0f;
        }
    }

    // Reduce the 4 groups -> lanes 0..15 get full feature sums.
    a.x += __shfl_xor(a.x, 16); a.y += __shfl_xor(a.y, 16);
    a.z += __shfl_xor(a.z, 16); a.w += __shfl_xor(a.w, 16);
    a.x += __shfl_xor(a.x, 32); a.y += __shfl_xor(a.y, 32);
    a.z += __shfl_xor(a.z, 32); a.w += __shfl_xor(a.w, 32);

    // x = mean + src, staged to LDS by lanes 0..15.
    if (lane < 16) {
        const float inv = 1.0f / fmaxf((float)cnt, 1.0f);
        float4 xv;
        xv.x = fmaf(a.x, inv, s4.x);
        xv.y = fmaf(a.y, inv, s4.y);
        xv.z = fmaf(a.z, inv, s4.z);
        xv.w = fmaf(a.w, inv, s4.w);
        *((float4*)&sx[wave][0] + f) = xv;
    }
    // same-wave LDS RAW: compiler inserts lgkmcnt wait; each wave only
    // touches sx[wave] -> no barrier needed.

    // out[node][lane] = b[lane] + sum_k x[k] * W[k][lane]
    float acc = bv[lane];
#pragma unroll
    for (int k = 0; k < D; k += 4) {
        const float4 xk = *(const float4*)&sx[wave][k];  // broadcast
        acc = fmaf(xk.x, sW[k + 0][lane], acc);          // stride-1: conflict-free
        acc = fmaf(xk.y, sW[k + 1][lane], acc);
        acc = fmaf(xk.z, sW[k + 2][lane], acc);
        acc = fmaf(xk.w, sW[k + 3][lane], acc);
    }
    out[(size_t)node * D + lane] = acc;
}

extern "C" void kernel_launch(void* const* d_in, const int* in_sizes, int n_in,
                              void* d_out, int out_size, void* d_ws, size_t ws_size,
                              hipStream_t stream) {
    const float* src = (const float*)d_in[0];
    // d_in[1] = edge (unused by reference)
    const float* dst = (const float*)d_in[2];
    const int*   ids = (const int*)d_in[3];
    const float* Wm  = (const float*)d_in[4];
    const float* bv  = (const float*)d_in[5];
    float* out = (float*)d_out;

    const int n_nodes = in_sizes[0] / D;   // 50000
    const int n_edges = in_sizes[3];       // 1250000

    const int nblocks = (n_nodes + 3) / 4; // 12500

    if (ws_size >= (size_t)(n_nodes + 1) * sizeof(int)) {
        int* offs = (int*)d_ws;
        seg_bounds<<<(n_edges + 255) / 256, 256, 0, stream>>>(ids, offs, n_nodes, n_edges);
        gcn_fused<true><<<nblocks, 256, 0, stream>>>(src, dst, ids, offs, Wm, bv, out,
                                                     n_nodes, n_edges);
    } else {
        gcn_fused<false><<<nblocks, 256, 0, stream>>>(src, dst, ids, nullptr, Wm, bv, out,
                                                      n_nodes, n_edges);
    }
}